// Round 1
// baseline (186.024 us; speedup 1.0000x reference)
//
#include <hip/hip_runtime.h>
#include <math.h>

#define NELEM 262144   // 4*64*32*32
#define EPS_BN 1e-5f

// ---------------------------------------------------------------------------
// Adder2d with fused BN+ReLU on the *input* (staged through LDS).
// MODE 0: src = x (raw input), apply bn1+relu while staging.
// MODE 1: src = 4 channel-partial buffers from adder1 (positive sums);
//         staged value = relu(bn2(-(p0+p1+p2+p3))).
// Block decode: blk = b*64 + og*4 + cs   (b in [0,4), og in [0,16), cs in [0,4))
//   block computes outputs for o in [og*4, og*4+4), summing channels
//   c in [cs*16, cs*16+16), for batch b, full 32x32 spatial.
// Thread t: y = t>>3 (0..31), x0 = (t&7)*4 -> 4-wide spatial x 4 o's = 16 accs.
// Output: positive partial sums into pout[cs*NELEM + ...].
// ---------------------------------------------------------------------------
template<int MODE>
__global__ __launch_bounds__(256) void adder_kernel(
    const float* __restrict__ src, const float* __restrict__ w,
    const float* __restrict__ bng, const float* __restrict__ bnb,
    const float* __restrict__ bnm, const float* __restrict__ bnv,
    float* __restrict__ pout)
{
    // 8 channels staged at a time; stride 35 breaks bank aliasing.
    __shared__ float lds[8][34][35];

    const int blk = blockIdx.x;
    const int cs  = blk & 3;
    const int og  = (blk >> 2) & 15;
    const int b   = blk >> 6;
    const int c0  = cs * 16;
    const int t   = threadIdx.x;
    const int y   = t >> 3;
    const int x0  = (t & 7) * 4;

    float acc[4][4];
#pragma unroll
    for (int i = 0; i < 4; ++i)
#pragma unroll
        for (int j = 0; j < 4; ++j) acc[i][j] = 0.f;

    for (int ch = 0; ch < 16; ch += 8) {
        __syncthreads();   // protect LDS from previous chunk's readers
        // ---- stage 8 channels with zero halo, fused bn+relu ----
        for (int i = t; i < 8 * 34 * 34; i += 256) {
            int cc  = i / 1156;
            int rem = i - cc * 1156;
            int yy  = rem / 34;
            int xx  = rem - yy * 34;
            float val = 0.f;
            int gy = yy - 1, gx = xx - 1;
            if (gy >= 0 && gy < 32 && gx >= 0 && gx < 32) {
                int c   = c0 + ch + cc;
                int off = ((b * 64 + c) * 32 + gy) * 32 + gx;
                float u;
                if (MODE == 0) {
                    u = src[off];
                } else {
                    u = -(src[off] + src[off + NELEM] +
                          src[off + 2 * NELEM] + src[off + 3 * NELEM]);
                }
                float inv  = bng[c] * rsqrtf(bnv[c] + EPS_BN);
                float beta = bnb[c] - bnm[c] * inv;
                val = fmaxf(fmaf(u, inv, beta), 0.f);
            }
            lds[cc][yy][xx] = val;
        }
        __syncthreads();
        // ---- compute: per channel, 18-float patch reused for 4 o x 4 x x 9 terms
        for (int cc = 0; cc < 8; ++cc) {
            const int c = c0 + ch + cc;
            float p[3][6];
#pragma unroll
            for (int r = 0; r < 3; ++r)
#pragma unroll
                for (int j = 0; j < 6; ++j)
                    p[r][j] = lds[cc][y + r][x0 + j];
#pragma unroll
            for (int oo = 0; oo < 4; ++oo) {
                const float* wp = w + ((og * 4 + oo) * 64 + c) * 9;  // block-uniform -> s_load
#pragma unroll
                for (int kh = 0; kh < 3; ++kh)
#pragma unroll
                    for (int kw = 0; kw < 3; ++kw) {
                        float wv = wp[kh * 3 + kw];
#pragma unroll
                        for (int xi = 0; xi < 4; ++xi)
                            acc[oo][xi] += fabsf(p[kh][kw + xi] - wv);
                    }
            }
        }
    }

    // ---- write positive partial sums (negation applied at combine) ----
#pragma unroll
    for (int oo = 0; oo < 4; ++oo) {
        int o   = og * 4 + oo;
        int off = ((b * 64 + o) * 32 + y) * 32 + x0;
        float4 r = make_float4(acc[oo][0], acc[oo][1], acc[oo][2], acc[oo][3]);
        *reinterpret_cast<float4*>(pout + (size_t)cs * NELEM + off) = r;
    }
}

// ---------------------------------------------------------------------------
// Combine adder2's 4 channel-partials -> out2 = -(p0+p1+p2+p3), and compute
// per-(b,o) spatial mean s[b*64+o]. One block per (b,o) image (1024 elems).
// ---------------------------------------------------------------------------
__global__ __launch_bounds__(256) void combine_kernel(
    const float* __restrict__ p, float* __restrict__ out2, float* __restrict__ s)
{
    const int blk  = blockIdx.x;   // 0..255 = b*64+o
    const int t    = threadIdx.x;
    const int base = blk * 1024 + t * 4;

    float4 a  = *reinterpret_cast<const float4*>(p + base);
    float4 b4 = *reinterpret_cast<const float4*>(p + NELEM + base);
    float4 c4 = *reinterpret_cast<const float4*>(p + 2 * NELEM + base);
    float4 d4 = *reinterpret_cast<const float4*>(p + 3 * NELEM + base);
    float4 r;
    r.x = -(a.x + b4.x + c4.x + d4.x);
    r.y = -(a.y + b4.y + c4.y + d4.y);
    r.z = -(a.z + b4.z + c4.z + d4.z);
    r.w = -(a.w + b4.w + c4.w + d4.w);
    *reinterpret_cast<float4*>(out2 + base) = r;

    float local = r.x + r.y + r.z + r.w;
#pragma unroll
    for (int off = 32; off > 0; off >>= 1)
        local += __shfl_down(local, off, 64);

    __shared__ float red[4];
    if ((t & 63) == 0) red[t >> 6] = local;
    __syncthreads();
    if (t == 0)
        s[blk] = (red[0] + red[1] + red[2] + red[3]) * (1.f / 1024.f);
}

// ---------------------------------------------------------------------------
// SE gate + apply + shortcut. One block per (b,o): g = sigmoid(fc2(relu(fc1(s))))
// computed redundantly per thread (cheap), then out = out2*g + x.
// ---------------------------------------------------------------------------
__global__ __launch_bounds__(256) void gate_kernel(
    const float* __restrict__ out2, const float* __restrict__ x,
    const float* __restrict__ s,
    const float* __restrict__ fc1w, const float* __restrict__ fc1b,
    const float* __restrict__ fc2w, const float* __restrict__ fc2b,
    float* __restrict__ out)
{
    const int blk = blockIdx.x;      // b*64 + o
    const int b   = blk >> 6;
    const int o   = blk & 63;
    const int t   = threadIdx.x;

    __shared__ float ss[64];
    if (t < 64) ss[t] = s[b * 64 + t];
    __syncthreads();

    float h[4];
#pragma unroll
    for (int j = 0; j < 4; ++j) {
        float a = fc1b[j];
#pragma unroll
        for (int c = 0; c < 64; ++c) a += ss[c] * fc1w[j * 64 + c];
        h[j] = fmaxf(a, 0.f);
    }
    float z = fc2b[o];
#pragma unroll
    for (int j = 0; j < 4; ++j) z += h[j] * fc2w[o * 4 + j];
    float g = 1.f / (1.f + __expf(-z));

    const int base = blk * 1024 + t * 4;
    float4 v  = *reinterpret_cast<const float4*>(out2 + base);
    float4 xv = *reinterpret_cast<const float4*>(x + base);
    float4 r;
    r.x = v.x * g + xv.x;
    r.y = v.y * g + xv.y;
    r.z = v.z * g + xv.z;
    r.w = v.w * g + xv.w;
    *reinterpret_cast<float4*>(out + base) = r;
}

// ---------------------------------------------------------------------------
extern "C" void kernel_launch(void* const* d_in, const int* in_sizes, int n_in,
                              void* d_out, int out_size, void* d_ws, size_t ws_size,
                              hipStream_t stream)
{
    const float* x     = (const float*)d_in[0];
    const float* bn1g  = (const float*)d_in[1];
    const float* bn1b  = (const float*)d_in[2];
    const float* bn1m  = (const float*)d_in[3];
    const float* bn1v  = (const float*)d_in[4];
    const float* w1    = (const float*)d_in[5];
    const float* bn2g  = (const float*)d_in[6];
    const float* bn2b  = (const float*)d_in[7];
    const float* bn2m  = (const float*)d_in[8];
    const float* bn2v  = (const float*)d_in[9];
    const float* w2    = (const float*)d_in[10];
    const float* fc1w  = (const float*)d_in[11];
    const float* fc1b  = (const float*)d_in[12];
    const float* fc2w  = (const float*)d_in[13];
    const float* fc2b  = (const float*)d_in[14];

    float* ws   = (float*)d_ws;
    float* p1   = ws;                         // 4 * NELEM
    float* p2   = ws + 4 * (size_t)NELEM;     // 4 * NELEM
    float* out2 = ws + 8 * (size_t)NELEM;     // NELEM
    float* sbuf = ws + 9 * (size_t)NELEM;     // 256

    adder_kernel<0><<<256, 256, 0, stream>>>(x,  w1, bn1g, bn1b, bn1m, bn1v, p1);
    adder_kernel<1><<<256, 256, 0, stream>>>(p1, w2, bn2g, bn2b, bn2m, bn2v, p2);
    combine_kernel<<<256, 256, 0, stream>>>(p2, out2, sbuf);
    gate_kernel<<<256, 256, 0, stream>>>(out2, x, sbuf, fc1w, fc1b, fc2w, fc2b,
                                         (float*)d_out);
}

// Round 2
// 133.709 us; speedup vs baseline: 1.3913x; 1.3913x over previous
//
#include <hip/hip_runtime.h>
#include <math.h>

#define NELEM 262144   // 4*64*32*32
#define EPS_BN 1e-5f

// ---------------------------------------------------------------------------
// Adder2d, full 64-channel reduction per block (no partial buffers).
// Grid: 1024 blocks = b(4) x og(32, 2 outputs each) x sp(8, 4-row strips).
// Threads 256: pos = t&31 (4 rows x 8 xgroups of 4), cq = t>>5 (8 channel
// groups of 8 channels). Per-thread 2o x 4x accumulators; cq-reduced via LDS.
// MODE 0: stage relu(bn1(x)).  MODE 1: stage relu(bn2(src)), and fuse the
// per-(b,o) spatial sum (for SE mean) via wave-reduce + atomicAdd to sbuf.
// Output written NEGATED (final adder value).
// ---------------------------------------------------------------------------
template<int MODE>
__global__ __launch_bounds__(256, 4) void adder_kernel(
    const float* __restrict__ src, const float* __restrict__ w,
    const float* __restrict__ bng, const float* __restrict__ bnb,
    const float* __restrict__ bnm, const float* __restrict__ bnv,
    float* __restrict__ out, float* __restrict__ sbuf)
{
    // tile: 32 ch x 6 rows (4 + 2 halo) x 36 cols (16B-aligned rows, cols
    // 0 and 33 are the zero halo, 34/35 pad). Aliased with the cq-reduction
    // buffer (used strictly after the last tile read + barrier).
    __shared__ union {
        float tile[32][6][36];          // 27648 B
        float red[8][32][2][4];         // 8192 B
    } sh;
    __shared__ float wlds[2][64][12];   // 6144 B, padded to 12 for 16B align
    __shared__ float binv[64], bbeta[64];

    const int blk = blockIdx.x;
    const int sp  = blk & 7;            // row strip: rows [sp*4, sp*4+4)
    const int og  = (blk >> 3) & 31;    // outputs og*2, og*2+1
    const int b   = blk >> 8;
    const int t   = threadIdx.x;
    const int pos = t & 31;
    const int cq  = t >> 5;
    const int y_i = pos >> 3;           // 0..3
    const int x0  = (pos & 7) * 4;      // 0..28

    // bn scale/bias precompute (once per block)
    if (t < 64) {
        float inv = bng[t] * rsqrtf(bnv[t] + EPS_BN);
        binv[t]  = inv;
        bbeta[t] = bnb[t] - bnm[t] * inv;
    }
    // weight preload: 2 o x 64 c x 9
    for (int i = t; i < 1152; i += 256) {
        int o_i = i / 576;
        int rem = i - o_i * 576;
        int c   = rem / 9;
        int k   = rem - c * 9;
        wlds[o_i][c][k] = w[(og * 2 + o_i) * 576 + c * 9 + k];
    }

    float acc[2][4];
#pragma unroll
    for (int oo = 0; oo < 2; ++oo)
#pragma unroll
        for (int xi = 0; xi < 4; ++xi) acc[oo][xi] = 0.f;

    for (int ch0 = 0; ch0 < 64; ch0 += 32) {
        __syncthreads();   // protect tile from previous chunk's readers
                           // (also makes binv/wlds visible on first pass)
        // ---- stage interior cols 1..32 via float4: 32ch x 6rows x 8 groups
#pragma unroll
        for (int k = 0; k < 6; ++k) {
            int i   = t + k * 256;             // 0..1535
            int cc  = i / 48;
            int rem = i - cc * 48;
            int yy  = rem >> 3;
            int gx  = (rem & 7) * 4;
            int gy  = sp * 4 - 1 + yy;
            int c   = ch0 + cc;
            float4 v = make_float4(0.f, 0.f, 0.f, 0.f);
            if (gy >= 0 && gy < 32) {
                const float4 u = *reinterpret_cast<const float4*>(
                    src + (((b * 64 + c) * 32 + gy) * 32 + gx));
                float inv = binv[c], bet = bbeta[c];
                v.x = fmaxf(fmaf(u.x, inv, bet), 0.f);
                v.y = fmaxf(fmaf(u.y, inv, bet), 0.f);
                v.z = fmaxf(fmaf(u.z, inv, bet), 0.f);
                v.w = fmaxf(fmaf(u.w, inv, bet), 0.f);
            }
            float* dst = &sh.tile[cc][yy][1 + gx];
            dst[0] = v.x; dst[1] = v.y; dst[2] = v.z; dst[3] = v.w;
        }
        // ---- zero halo columns 0 and 33: 32ch x 6rows x 2
        for (int i = t; i < 384; i += 256) {
            int cc  = i / 12;
            int rem = i - cc * 12;
            int yy  = rem >> 1;
            sh.tile[cc][yy][(rem & 1) ? 33 : 0] = 0.f;
        }
        __syncthreads();

        // ---- compute: 4 channels per thread in this chunk
        for (int j = 0; j < 4; ++j) {
            int cl = cq * 4 + j;           // tile channel
            int c  = ch0 + cl;             // global channel
            float p[3][6];
#pragma unroll
            for (int r = 0; r < 3; ++r) {
                float4 a  = *reinterpret_cast<const float4*>(&sh.tile[cl][y_i + r][x0]);
                float2 b2 = *reinterpret_cast<const float2*>(&sh.tile[cl][y_i + r][x0 + 4]);
                p[r][0] = a.x; p[r][1] = a.y; p[r][2] = a.z; p[r][3] = a.w;
                p[r][4] = b2.x; p[r][5] = b2.y;
            }
#pragma unroll
            for (int oo = 0; oo < 2; ++oo) {
                float4 w03 = *reinterpret_cast<const float4*>(&wlds[oo][c][0]);
                float4 w47 = *reinterpret_cast<const float4*>(&wlds[oo][c][4]);
                float  w8  = wlds[oo][c][8];
                float wv[9] = {w03.x, w03.y, w03.z, w03.w,
                               w47.x, w47.y, w47.z, w47.w, w8};
#pragma unroll
                for (int kh = 0; kh < 3; ++kh)
#pragma unroll
                    for (int kw = 0; kw < 3; ++kw) {
                        float wvv = wv[kh * 3 + kw];
#pragma unroll
                        for (int xi = 0; xi < 4; ++xi)
                            acc[oo][xi] += fabsf(p[kh][kw + xi] - wvv);
                    }
            }
        }
    }

    // ---- cq reduction through LDS (tile no longer needed) ----
    __syncthreads();
    {
        float* dst = &sh.red[cq][pos][0][0];
        *reinterpret_cast<float4*>(dst)     = make_float4(acc[0][0], acc[0][1], acc[0][2], acc[0][3]);
        *reinterpret_cast<float4*>(dst + 4) = make_float4(acc[1][0], acc[1][1], acc[1][2], acc[1][3]);
    }
    __syncthreads();

    const int oo = t >> 7;           // output within pair
    const int yo = (t >> 5) & 3;     // row within strip
    const int x  = t & 31;           // column
    const int p2 = yo * 8 + (x >> 2);
    const int xi = x & 3;
    float v = 0.f;
#pragma unroll
    for (int c8 = 0; c8 < 8; ++c8) v += sh.red[c8][p2][oo][xi];
    v = -v;

    const int o = og * 2 + oo;
    out[((b * 64 + o) * 32 + sp * 4 + yo) * 32 + x] = v;

    if (MODE == 1) {
        // fused spatial sum for SE mean: wave-uniform o (wave = t>>6 -> oo = t>>7)
        float sum = v;
#pragma unroll
        for (int off = 32; off > 0; off >>= 1)
            sum += __shfl_down(sum, off, 64);
        if ((t & 63) == 0) atomicAdd(&sbuf[b * 64 + o], sum);
    }
}

// ---------------------------------------------------------------------------
// SE gate + apply + shortcut. 1024 blocks x 64 threads; block = (b,o,quarter).
// sbuf holds spatial SUMS; mean = sum/1024.
// ---------------------------------------------------------------------------
__global__ __launch_bounds__(64) void gate_kernel(
    const float* __restrict__ out2, const float* __restrict__ x,
    const float* __restrict__ sbuf,
    const float* __restrict__ fc1w, const float* __restrict__ fc1b,
    const float* __restrict__ fc2w, const float* __restrict__ fc2b,
    float* __restrict__ out)
{
    const int blk = blockIdx.x;
    const int bo  = blk >> 2;        // b*64 + o
    const int q   = blk & 3;
    const int b   = bo >> 6;
    const int o   = bo & 63;
    const int t   = threadIdx.x;

    __shared__ float ss[64];
    ss[t] = sbuf[b * 64 + t] * (1.f / 1024.f);
    __syncthreads();

    float h[4];
#pragma unroll
    for (int j = 0; j < 4; ++j) {
        float a = fc1b[j];
#pragma unroll
        for (int c = 0; c < 64; ++c) a += ss[c] * fc1w[j * 64 + c];
        h[j] = fmaxf(a, 0.f);
    }
    float z = fc2b[o];
#pragma unroll
    for (int j = 0; j < 4; ++j) z += h[j] * fc2w[o * 4 + j];
    float g = 1.f / (1.f + __expf(-z));

    const int base = bo * 1024 + q * 256 + t * 4;
    float4 v  = *reinterpret_cast<const float4*>(out2 + base);
    float4 xv = *reinterpret_cast<const float4*>(x + base);
    float4 r;
    r.x = v.x * g + xv.x;
    r.y = v.y * g + xv.y;
    r.z = v.z * g + xv.z;
    r.w = v.w * g + xv.w;
    *reinterpret_cast<float4*>(out + base) = r;
}

// ---------------------------------------------------------------------------
extern "C" void kernel_launch(void* const* d_in, const int* in_sizes, int n_in,
                              void* d_out, int out_size, void* d_ws, size_t ws_size,
                              hipStream_t stream)
{
    const float* x    = (const float*)d_in[0];
    const float* bn1g = (const float*)d_in[1];
    const float* bn1b = (const float*)d_in[2];
    const float* bn1m = (const float*)d_in[3];
    const float* bn1v = (const float*)d_in[4];
    const float* w1   = (const float*)d_in[5];
    const float* bn2g = (const float*)d_in[6];
    const float* bn2b = (const float*)d_in[7];
    const float* bn2m = (const float*)d_in[8];
    const float* bn2v = (const float*)d_in[9];
    const float* w2   = (const float*)d_in[10];
    const float* fc1w = (const float*)d_in[11];
    const float* fc1b = (const float*)d_in[12];
    const float* fc2w = (const float*)d_in[13];
    const float* fc2b = (const float*)d_in[14];

    float* ws   = (float*)d_ws;
    float* out1 = ws;                     // NELEM
    float* out2 = ws + NELEM;             // NELEM
    float* sbuf = ws + 2 * (size_t)NELEM; // 256

    hipMemsetAsync(sbuf, 0, 256 * sizeof(float), stream);
    adder_kernel<0><<<1024, 256, 0, stream>>>(x,    w1, bn1g, bn1b, bn1m, bn1v,
                                              out1, nullptr);
    adder_kernel<1><<<1024, 256, 0, stream>>>(out1, w2, bn2g, bn2b, bn2m, bn2v,
                                              out2, sbuf);
    gate_kernel<<<1024, 64, 0, stream>>>(out2, x, sbuf, fc1w, fc1b, fc2w, fc2b,
                                         (float*)d_out);
}

// Round 3
// 132.010 us; speedup vs baseline: 1.4092x; 1.0129x over previous
//
#include <hip/hip_runtime.h>
#include <math.h>

#define NELEM   262144          // 4*64*32*32
#define NW      36864           // 64*64*3*3
#define EPS_BN  1e-5f
#define QSCALE  65536.0f
#define QBIAS_F (16.0f * 65536.0f + 0.5f)   // quant bias incl. +0.5 rounding
#define QB_U    1048576u                     // 16*65536: quantized zero (halo)
#define QINV    (1.0f / 65536.0f)

// v_sad_u32: acc += |a - b|  (single VOP3 instruction)
__device__ __forceinline__ unsigned sad_acc(unsigned a, unsigned b, unsigned acc) {
    asm("v_sad_u32 %0, %1, %2, %0" : "+v"(acc) : "v"(a), "v"(b));
    return acc;
}

// ---------------------------------------------------------------------------
// prep: qx = quant(relu(bn1(x))); qw1/qw2 = quant(w); bn2c = {-inv2/2^16, beta2}
// ---------------------------------------------------------------------------
__global__ __launch_bounds__(256) void prep_kernel(
    const float* __restrict__ x,
    const float* __restrict__ g1, const float* __restrict__ b1,
    const float* __restrict__ m1, const float* __restrict__ v1,
    const float* __restrict__ w1,
    const float* __restrict__ g2, const float* __restrict__ b2,
    const float* __restrict__ m2, const float* __restrict__ v2,
    const float* __restrict__ w2,
    unsigned* __restrict__ qx, unsigned* __restrict__ qw1,
    unsigned* __restrict__ qw2, float* __restrict__ bn2c)
{
    int i = blockIdx.x * 256 + threadIdx.x;
    if (i < NELEM) {
        int c = (i >> 10) & 63;
        float inv = g1[c] * rsqrtf(v1[c] + EPS_BN);
        float bet = b1[c] - m1[c] * inv;
        float a = fmaxf(fmaf(x[i], inv, bet), 0.f);
        qx[i] = (unsigned)fmaf(a, QSCALE, QBIAS_F);
    }
    int j = i - NELEM;
    if (j >= 0 && j < NW) qw1[j] = (unsigned)fmaf(w1[j], QSCALE, QBIAS_F);
    int k = j - NW;
    if (k >= 0 && k < NW) qw2[k] = (unsigned)fmaf(w2[k], QSCALE, QBIAS_F);
    int l = k - NW;
    if (l >= 0 && l < 64) {
        float inv = g2[l] * rsqrtf(v2[l] + EPS_BN);
        bn2c[l]      = -inv * QINV;            // maps u32 acc -> bn2 pre-act
        bn2c[l + 64] = b2[l] - m2[l] * inv;
    }
}

// ---------------------------------------------------------------------------
// Adder2d on quantized inputs via v_sad_u32.
// Grid 1024 = b(4) x og(32: 2 outputs) x sp(8: 4-row strips); 256 threads:
//   cq = t>>4 (16 channel groups of 2/chunk), pos = t&15: y_i=pos>>2,
//   x0=(pos&3)*8 -> per-thread 2 o x 8 x accumulators (u32).
// MODE 0: epilogue writes qout = quant(relu(bn2(-acc/2^16))).
// MODE 1: epilogue writes float out2 = -acc/2^16 and SE spatial-sum atomics.
// ---------------------------------------------------------------------------
template<int MODE>
__global__ __launch_bounds__(256, 4) void adder_kernel(
    const unsigned* __restrict__ qsrc, const unsigned* __restrict__ qw,
    const float* __restrict__ bn2c,
    unsigned* __restrict__ qout, float* __restrict__ fout,
    float* __restrict__ sbuf)
{
    __shared__ union {
        unsigned tile[32][6][36];   // 27648 B: 32ch x (4+2 halo rows) x 36 cols
        unsigned red[16][16][16];   // 16384 B: cq x pos x (2o*8x)
    } sh;
    __shared__ unsigned wlds[2][64][12];  // 6144 B (12-pad: 48B rows, 16B-aligned)

    const int blk = blockIdx.x;
    const int sp  = blk & 7;
    const int og  = (blk >> 3) & 31;
    const int b   = blk >> 8;
    const int t   = threadIdx.x;
    const int pos = t & 15;
    const int cq  = t >> 4;
    const int y_i = pos >> 2;
    const int x0  = (pos & 3) * 8;

    // weight preload: 2 o x 64 c x 9 (u32)
    for (int i = t; i < 1152; i += 256) {
        int o_i = i / 576;
        int rem = i - o_i * 576;
        int c   = rem / 9;
        int kk  = rem - c * 9;
        wlds[o_i][c][kk] = qw[(og * 2 + o_i) * 576 + c * 9 + kk];
    }

    unsigned acc[2][8];
#pragma unroll
    for (int oo = 0; oo < 2; ++oo)
#pragma unroll
        for (int xi = 0; xi < 8; ++xi) acc[oo][xi] = 0u;

    for (int ch0 = 0; ch0 < 64; ch0 += 32) {
        __syncthreads();
        // ---- stage 32 ch x 6 rows x 32 interior cols, raw u32 copy ----
#pragma unroll
        for (int kk = 0; kk < 6; ++kk) {
            int i   = t + kk * 256;        // 0..1535
            int cc  = i / 48;
            int rem = i - cc * 48;
            int yy  = rem >> 3;
            int gx  = (rem & 7) * 4;
            int gy  = sp * 4 - 1 + yy;
            uint4 v = make_uint4(QB_U, QB_U, QB_U, QB_U);
            if (gy >= 0 && gy < 32)
                v = *reinterpret_cast<const uint4*>(
                    qsrc + (((b * 64 + ch0 + cc) * 32 + gy) * 32 + gx));
            unsigned* dst = &sh.tile[cc][yy][1 + gx];
            dst[0] = v.x; dst[1] = v.y; dst[2] = v.z; dst[3] = v.w;
        }
        // halo cols 0 and 33 = quantized zero
        for (int i = t; i < 384; i += 256) {
            int cc  = i / 12;
            int rem = i - cc * 12;
            int yy  = rem >> 1;
            sh.tile[cc][yy][(rem & 1) ? 33 : 0] = QB_U;
        }
        __syncthreads();

        // ---- compute: 2 channels per thread per chunk ----
#pragma unroll
        for (int j = 0; j < 2; ++j) {
            const int cl = cq * 2 + j;
            const int c  = ch0 + cl;
            unsigned p[3][12];
#pragma unroll
            for (int r = 0; r < 3; ++r) {
                uint4 a0 = *reinterpret_cast<const uint4*>(&sh.tile[cl][y_i + r][x0]);
                uint4 a1 = *reinterpret_cast<const uint4*>(&sh.tile[cl][y_i + r][x0 + 4]);
                uint4 a2 = *reinterpret_cast<const uint4*>(&sh.tile[cl][y_i + r][x0 + 8]);
                p[r][0] = a0.x; p[r][1]  = a0.y; p[r][2]  = a0.z; p[r][3]  = a0.w;
                p[r][4] = a1.x; p[r][5]  = a1.y; p[r][6]  = a1.z; p[r][7]  = a1.w;
                p[r][8] = a2.x; p[r][9]  = a2.y; p[r][10] = a2.z; p[r][11] = a2.w;
            }
#pragma unroll
            for (int oo = 0; oo < 2; ++oo) {
                uint4 wa = *reinterpret_cast<const uint4*>(&wlds[oo][c][0]);
                uint4 wb = *reinterpret_cast<const uint4*>(&wlds[oo][c][4]);
                unsigned w8 = wlds[oo][c][8];
                unsigned wv[9] = {wa.x, wa.y, wa.z, wa.w,
                                  wb.x, wb.y, wb.z, wb.w, w8};
#pragma unroll
                for (int kh = 0; kh < 3; ++kh)
#pragma unroll
                    for (int kw = 0; kw < 3; ++kw) {
                        unsigned ww = wv[kh * 3 + kw];
#pragma unroll
                        for (int xi = 0; xi < 8; ++xi)
                            acc[oo][xi] = sad_acc(p[kh][xi + kw], ww, acc[oo][xi]);
                    }
            }
        }
    }

    // ---- cq reduction via LDS (tile dead; red aliases it) ----
    __syncthreads();
    {
        unsigned* dst = &sh.red[cq][pos][0];
        *reinterpret_cast<uint4*>(dst + 0)  = make_uint4(acc[0][0], acc[0][1], acc[0][2], acc[0][3]);
        *reinterpret_cast<uint4*>(dst + 4)  = make_uint4(acc[0][4], acc[0][5], acc[0][6], acc[0][7]);
        *reinterpret_cast<uint4*>(dst + 8)  = make_uint4(acc[1][0], acc[1][1], acc[1][2], acc[1][3]);
        *reinterpret_cast<uint4*>(dst + 12) = make_uint4(acc[1][4], acc[1][5], acc[1][6], acc[1][7]);
    }
    __syncthreads();

    const int oo2 = t >> 7;
    const int s   = t & 127;
    const int yy2 = s >> 5;
    const int xx2 = s & 31;
    const int pp  = yy2 * 4 + (xx2 >> 3);
    const int z   = (oo2 << 3) | (xx2 & 7);
    unsigned total = 0;
#pragma unroll
    for (int q = 0; q < 16; ++q) total += sh.red[q][pp][z];

    const int o   = og * 2 + oo2;
    const int idx = ((b * 64 + o) * 32 + sp * 4 + yy2) * 32 + xx2;
    const float accf = (float)total;

    if (MODE == 0) {
        float a2 = fmaxf(fmaf(accf, bn2c[o], bn2c[o + 64]), 0.f);
        qout[idx] = (unsigned)fmaf(a2, QSCALE, QBIAS_F);
    } else {
        float v = -accf * QINV;
        fout[idx] = v;
        float sum = v;
#pragma unroll
        for (int off = 32; off > 0; off >>= 1)
            sum += __shfl_down(sum, off, 64);
        if ((t & 63) == 0) atomicAdd(&sbuf[b * 64 + o], sum);
    }
}

// ---------------------------------------------------------------------------
// SE gate + apply + shortcut. 256 blocks (one per b,o image) x 256 threads.
// ---------------------------------------------------------------------------
__global__ __launch_bounds__(256) void gate_kernel(
    const float* __restrict__ out2, const float* __restrict__ x,
    const float* __restrict__ sbuf,
    const float* __restrict__ fc1w, const float* __restrict__ fc1b,
    const float* __restrict__ fc2w, const float* __restrict__ fc2b,
    float* __restrict__ out)
{
    const int bo = blockIdx.x;
    const int b  = bo >> 6;
    const int o  = bo & 63;
    const int t  = threadIdx.x;

    __shared__ float ss[64];
    if (t < 64) ss[t] = sbuf[b * 64 + t] * (1.f / 1024.f);
    __syncthreads();

    float h[4];
#pragma unroll
    for (int j = 0; j < 4; ++j) {
        float a = fc1b[j];
#pragma unroll
        for (int c = 0; c < 64; ++c) a += ss[c] * fc1w[j * 64 + c];
        h[j] = fmaxf(a, 0.f);
    }
    float zz = fc2b[o];
#pragma unroll
    for (int j = 0; j < 4; ++j) zz += h[j] * fc2w[o * 4 + j];
    float g = 1.f / (1.f + __expf(-zz));

    const int base = bo * 1024 + t * 4;
    float4 v  = *reinterpret_cast<const float4*>(out2 + base);
    float4 xv = *reinterpret_cast<const float4*>(x + base);
    float4 r;
    r.x = v.x * g + xv.x;
    r.y = v.y * g + xv.y;
    r.z = v.z * g + xv.z;
    r.w = v.w * g + xv.w;
    *reinterpret_cast<float4*>(out + base) = r;
}

// ---------------------------------------------------------------------------
extern "C" void kernel_launch(void* const* d_in, const int* in_sizes, int n_in,
                              void* d_out, int out_size, void* d_ws, size_t ws_size,
                              hipStream_t stream)
{
    const float* x    = (const float*)d_in[0];
    const float* bn1g = (const float*)d_in[1];
    const float* bn1b = (const float*)d_in[2];
    const float* bn1m = (const float*)d_in[3];
    const float* bn1v = (const float*)d_in[4];
    const float* w1   = (const float*)d_in[5];
    const float* bn2g = (const float*)d_in[6];
    const float* bn2b = (const float*)d_in[7];
    const float* bn2m = (const float*)d_in[8];
    const float* bn2v = (const float*)d_in[9];
    const float* w2   = (const float*)d_in[10];
    const float* fc1w = (const float*)d_in[11];
    const float* fc1b = (const float*)d_in[12];
    const float* fc2w = (const float*)d_in[13];
    const float* fc2b = (const float*)d_in[14];

    unsigned* ws    = (unsigned*)d_ws;
    unsigned* qx    = ws;                         // NELEM
    unsigned* qout1 = ws + NELEM;                 // NELEM
    float*    out2  = (float*)(ws + 2 * NELEM);   // NELEM
    unsigned* qw1   = ws + 3 * NELEM;             // NW
    unsigned* qw2   = ws + 3 * NELEM + NW;        // NW
    float*    bn2c  = (float*)(ws + 3 * NELEM + 2 * NW);        // 128
    float*    sbuf  = (float*)(ws + 3 * NELEM + 2 * NW + 128);  // 256

    hipMemsetAsync(sbuf, 0, 256 * sizeof(float), stream);
    prep_kernel<<<1313, 256, 0, stream>>>(x, bn1g, bn1b, bn1m, bn1v, w1,
                                          bn2g, bn2b, bn2m, bn2v, w2,
                                          qx, qw1, qw2, bn2c);
    adder_kernel<0><<<1024, 256, 0, stream>>>(qx,    qw1, bn2c, qout1, nullptr, nullptr);
    adder_kernel<1><<<1024, 256, 0, stream>>>(qout1, qw2, nullptr, nullptr, out2, sbuf);
    gate_kernel<<<256, 256, 0, stream>>>(out2, x, sbuf, fc1w, fc1b, fc2w, fc2b,
                                         (float*)d_out);
}

// Round 4
// 114.710 us; speedup vs baseline: 1.6217x; 1.1508x over previous
//
#include <hip/hip_runtime.h>
#include <math.h>

#define NELEM   262144            // 4*64*32*32
#define NW      36864             // 64*64*3*3
#define PIMG    1296              // 36*36 padded image stride per (b,c)
#define PADN    331776            // 4*64*36*36
#define NBORD   295936            // 4*64*34*34
#define EPS_BN  1e-5f
#define QSCALE  65536.0f
#define QBIAS_F (16.0f * 65536.0f + 0.5f)
#define QB_U    1048576u          // quantized 0.0
#define QINV    (1.0f / 65536.0f)

__device__ __forceinline__ unsigned sad_acc(unsigned a, unsigned b, unsigned acc) {
    asm("v_sad_u32 %0, %1, %2, %0" : "+v"(acc) : "v"(a), "v"(b));
    return acc;
}

// ---------------------------------------------------------------------------
// prep: builds padded quantized input  qxp[4][64][36][36] (rows/cols 0..33
// valid, halo=QB_U), writes qout1p's halo, quantizes w1/w2, computes bn2
// constants, zeroes sbuf. One elementwise kernel, segmented index.
// ---------------------------------------------------------------------------
__global__ __launch_bounds__(256) void prep_kernel(
    const float* __restrict__ x,
    const float* __restrict__ g1, const float* __restrict__ b1,
    const float* __restrict__ m1, const float* __restrict__ v1,
    const float* __restrict__ w1,
    const float* __restrict__ g2, const float* __restrict__ b2,
    const float* __restrict__ m2, const float* __restrict__ v2,
    const float* __restrict__ w2,
    unsigned* __restrict__ qxp, unsigned* __restrict__ qout1p,
    unsigned* __restrict__ qw1, unsigned* __restrict__ qw2,
    float* __restrict__ bn2c, float* __restrict__ sbuf)
{
    int i = blockIdx.x * 256 + threadIdx.x;
    if (i < NBORD) {                              // qxp: full 34x34 padded
        int bc  = i / 1156;                       // b*64+c
        int rc  = i - bc * 1156;
        int r   = rc / 34;
        int col = rc - r * 34;
        unsigned q = QB_U;
        if (r > 0 && r < 33 && col > 0 && col < 33) {
            int c = bc & 63;
            float inv = g1[c] * rsqrtf(v1[c] + EPS_BN);
            float bet = b1[c] - m1[c] * inv;
            float a = fmaxf(fmaf(x[(bc * 32 + (r - 1)) * 32 + (col - 1)], inv, bet), 0.f);
            q = (unsigned)fmaf(a, QSCALE, QBIAS_F);
        }
        qxp[bc * PIMG + r * 36 + col] = q;
        return;
    }
    int j = i - NBORD;
    if (j < NBORD) {                              // qout1p halo only
        int bc  = j / 1156;
        int rc  = j - bc * 1156;
        int r   = rc / 34;
        int col = rc - r * 34;
        if (r == 0 || r == 33 || col == 0 || col == 33)
            qout1p[bc * PIMG + r * 36 + col] = QB_U;
        return;
    }
    int k = j - NBORD;
    if (k < NW) { qw1[k] = (unsigned)fmaf(w1[k], QSCALE, QBIAS_F); return; }
    int l = k - NW;
    if (l < NW) { qw2[l] = (unsigned)fmaf(w2[l], QSCALE, QBIAS_F); return; }
    int m = l - NW;
    if (m < 64) {
        float inv = g2[m] * rsqrtf(v2[m] + EPS_BN);
        bn2c[m]      = -inv * QINV;
        bn2c[m + 64] = b2[m] - m2[m] * inv;
    }
    int s = m - 64;
    if (s >= 0 && s < 256) sbuf[s] = 0.f;
}

// ---------------------------------------------------------------------------
// Adder2d, barrier-free main loop: per-thread patch loaded straight from the
// padded global buffer (L1/L2-resident), weights in LDS (one barrier total).
// Grid 1024 = b(4) x og(32: 2 outputs) x sp(8: 4-row strips); 256 threads:
//   pos = t&15 (y_i = pos>>2, x0 = (pos&3)*8), cq = t>>4 -> 4 channels each.
// MODE 0: writes quant(relu(bn2(-acc))) into padded qout buffer.
// MODE 1: writes float out2 (std layout) + SE spatial-sum atomics.
// ---------------------------------------------------------------------------
template<int MODE>
__global__ __launch_bounds__(256, 4) void adder_kernel(
    const unsigned* __restrict__ qsrc, const unsigned* __restrict__ qw,
    const float* __restrict__ bn2c,
    unsigned* __restrict__ qout, float* __restrict__ fout,
    float* __restrict__ sbuf)
{
    __shared__ unsigned wlds[2][64][12];     // 6144 B
    __shared__ unsigned red[16][16][16];     // 16384 B

    const int blk = blockIdx.x;
    const int sp  = blk & 7;
    const int og  = (blk >> 3) & 31;
    const int b   = blk >> 8;
    const int t   = threadIdx.x;
    const int pos = t & 15;
    const int cq  = t >> 4;
    const int y_i = pos >> 2;
    const int x0  = (pos & 3) * 8;

    for (int i = t; i < 1152; i += 256) {
        int o_i = i / 576;
        int rem = i - o_i * 576;
        int c   = rem / 9;
        int kk  = rem - c * 9;
        wlds[o_i][c][kk] = qw[(og * 2 + o_i) * 576 + c * 9 + kk];
    }
    __syncthreads();

    unsigned acc[2][8];
#pragma unroll
    for (int oo = 0; oo < 2; ++oo)
#pragma unroll
        for (int xi = 0; xi < 8; ++xi) acc[oo][xi] = 0u;

    // patch top-left in padded coords: rows sp*4+y_i+r, cols x0..x0+11
    const unsigned* base = qsrc + (size_t)(b * 64 + cq * 4) * PIMG
                                + (sp * 4 + y_i) * 36 + x0;
#pragma unroll
    for (int j = 0; j < 4; ++j) {
        const unsigned* pc = base + j * PIMG;
        unsigned p[3][12];
#pragma unroll
        for (int r = 0; r < 3; ++r) {
            uint4 a0 = *reinterpret_cast<const uint4*>(pc + r * 36);
            uint4 a1 = *reinterpret_cast<const uint4*>(pc + r * 36 + 4);
            uint4 a2 = *reinterpret_cast<const uint4*>(pc + r * 36 + 8);
            p[r][0] = a0.x; p[r][1]  = a0.y; p[r][2]  = a0.z; p[r][3]  = a0.w;
            p[r][4] = a1.x; p[r][5]  = a1.y; p[r][6]  = a1.z; p[r][7]  = a1.w;
            p[r][8] = a2.x; p[r][9]  = a2.y; p[r][10] = a2.z; p[r][11] = a2.w;
        }
        const int c = cq * 4 + j;
#pragma unroll
        for (int oo = 0; oo < 2; ++oo) {
            uint4 wa = *reinterpret_cast<const uint4*>(&wlds[oo][c][0]);
            uint4 wb = *reinterpret_cast<const uint4*>(&wlds[oo][c][4]);
            unsigned w8 = wlds[oo][c][8];
            unsigned wv[9] = {wa.x, wa.y, wa.z, wa.w,
                              wb.x, wb.y, wb.z, wb.w, w8};
#pragma unroll
            for (int kh = 0; kh < 3; ++kh)
#pragma unroll
                for (int kw = 0; kw < 3; ++kw) {
                    unsigned ww = wv[kh * 3 + kw];
#pragma unroll
                    for (int xi = 0; xi < 8; ++xi)
                        acc[oo][xi] = sad_acc(p[kh][xi + kw], ww, acc[oo][xi]);
                }
        }
    }

    // ---- cq reduction via LDS ----
    {
        unsigned* dst = &red[cq][pos][0];
        *reinterpret_cast<uint4*>(dst + 0)  = make_uint4(acc[0][0], acc[0][1], acc[0][2], acc[0][3]);
        *reinterpret_cast<uint4*>(dst + 4)  = make_uint4(acc[0][4], acc[0][5], acc[0][6], acc[0][7]);
        *reinterpret_cast<uint4*>(dst + 8)  = make_uint4(acc[1][0], acc[1][1], acc[1][2], acc[1][3]);
        *reinterpret_cast<uint4*>(dst + 12) = make_uint4(acc[1][4], acc[1][5], acc[1][6], acc[1][7]);
    }
    __syncthreads();

    const int oo2 = t >> 7;
    const int s   = t & 127;
    const int yy2 = s >> 5;
    const int xx2 = s & 31;
    const int pp  = yy2 * 4 + (xx2 >> 3);
    const int z   = (oo2 << 3) | (xx2 & 7);
    unsigned total = 0;
#pragma unroll
    for (int q = 0; q < 16; ++q) total += red[q][pp][z];

    const int o    = og * 2 + oo2;
    const int gy   = sp * 4 + yy2;
    const float accf = (float)total;

    if (MODE == 0) {
        float a2 = fmaxf(fmaf(accf, bn2c[o], bn2c[o + 64]), 0.f);
        qout[(size_t)(b * 64 + o) * PIMG + (gy + 1) * 36 + (xx2 + 1)] =
            (unsigned)fmaf(a2, QSCALE, QBIAS_F);
    } else {
        float v = -accf * QINV;
        fout[((b * 64 + o) * 32 + gy) * 32 + xx2] = v;
        float sum = v;
#pragma unroll
        for (int off = 32; off > 0; off >>= 1)
            sum += __shfl_down(sum, off, 64);
        if ((t & 63) == 0) atomicAdd(&sbuf[b * 64 + o], sum);
    }
}

// ---------------------------------------------------------------------------
// SE gate + apply + shortcut. 256 blocks (one per b,o image) x 256 threads.
// ---------------------------------------------------------------------------
__global__ __launch_bounds__(256) void gate_kernel(
    const float* __restrict__ out2, const float* __restrict__ x,
    const float* __restrict__ sbuf,
    const float* __restrict__ fc1w, const float* __restrict__ fc1b,
    const float* __restrict__ fc2w, const float* __restrict__ fc2b,
    float* __restrict__ out)
{
    const int bo = blockIdx.x;
    const int b  = bo >> 6;
    const int o  = bo & 63;
    const int t  = threadIdx.x;

    __shared__ float ss[64];
    if (t < 64) ss[t] = sbuf[b * 64 + t] * (1.f / 1024.f);
    __syncthreads();

    float h[4];
#pragma unroll
    for (int j = 0; j < 4; ++j) {
        float a = fc1b[j];
#pragma unroll
        for (int c = 0; c < 64; ++c) a += ss[c] * fc1w[j * 64 + c];
        h[j] = fmaxf(a, 0.f);
    }
    float zz = fc2b[o];
#pragma unroll
    for (int j = 0; j < 4; ++j) zz += h[j] * fc2w[o * 4 + j];
    float g = 1.f / (1.f + __expf(-zz));

    const int base = bo * 1024 + t * 4;
    float4 v  = *reinterpret_cast<const float4*>(out2 + base);
    float4 xv = *reinterpret_cast<const float4*>(x + base);
    float4 r;
    r.x = v.x * g + xv.x;
    r.y = v.y * g + xv.y;
    r.z = v.z * g + xv.z;
    r.w = v.w * g + xv.w;
    *reinterpret_cast<float4*>(out + base) = r;
}

// ---------------------------------------------------------------------------
extern "C" void kernel_launch(void* const* d_in, const int* in_sizes, int n_in,
                              void* d_out, int out_size, void* d_ws, size_t ws_size,
                              hipStream_t stream)
{
    const float* x    = (const float*)d_in[0];
    const float* bn1g = (const float*)d_in[1];
    const float* bn1b = (const float*)d_in[2];
    const float* bn1m = (const float*)d_in[3];
    const float* bn1v = (const float*)d_in[4];
    const float* w1   = (const float*)d_in[5];
    const float* bn2g = (const float*)d_in[6];
    const float* bn2b = (const float*)d_in[7];
    const float* bn2m = (const float*)d_in[8];
    const float* bn2v = (const float*)d_in[9];
    const float* w2   = (const float*)d_in[10];
    const float* fc1w = (const float*)d_in[11];
    const float* fc1b = (const float*)d_in[12];
    const float* fc2w = (const float*)d_in[13];
    const float* fc2b = (const float*)d_in[14];

    unsigned* ws     = (unsigned*)d_ws;
    unsigned* qxp    = ws;                          // PADN
    unsigned* qout1p = ws + PADN;                   // PADN
    float*    out2   = (float*)(ws + 2 * PADN);     // NELEM
    unsigned* qw1    = ws + 2 * PADN + NELEM;       // NW
    unsigned* qw2    = ws + 2 * PADN + NELEM + NW;  // NW
    float*    bn2c   = (float*)(ws + 2 * PADN + NELEM + 2 * NW);        // 128
    float*    sbuf   = (float*)(ws + 2 * PADN + NELEM + 2 * NW + 128);  // 256

    // segments: NBORD + NBORD + NW + NW + 64 + 256 = 665,920 -> 2602 blocks
    prep_kernel<<<2602, 256, 0, stream>>>(x, bn1g, bn1b, bn1m, bn1v, w1,
                                          bn2g, bn2b, bn2m, bn2v, w2,
                                          qxp, qout1p, qw1, qw2, bn2c, sbuf);
    adder_kernel<0><<<1024, 256, 0, stream>>>(qxp,    qw1, bn2c, qout1p, nullptr, nullptr);
    adder_kernel<1><<<1024, 256, 0, stream>>>(qout1p, qw2, nullptr, nullptr, out2, sbuf);
    gate_kernel<<<256, 256, 0, stream>>>(out2, x, sbuf, fc1w, fc1b, fc2w, fc2b,
                                         (float*)d_out);
}